// Round 1
// baseline (567.444 us; speedup 1.0000x reference)
//
#include <hip/hip_runtime.h>
#include <cstdint>

#define EPS 1e-5f
#define INV_NTOT (1.0f / 1048576.0f)   // 1/(16*256*256)

// ws layout (float offsets):
//   [0, 1M)        h0  : conv1 output (16,1,256,256)
//   [1M, 2M)       fz  : fuzzify output
//   [2M, 2M+184)   stats: [0]=sum,[1]=sumsq, [2..10]=S[9], [11..55]=Q[45],
//                         [56..119]=scale[64], [120..183]=bias[64]
#define FZ_OFF  1048576
#define ST_OFF  2097152

__device__ __forceinline__ void dev_atomic_add(float* p, float v) {
    __hip_atomic_fetch_add(p, v, __ATOMIC_RELAXED, __HIP_MEMORY_SCOPE_AGENT);
}

// ---------------- K1: conv1 (64->1 ch, 3x3 SAME) + bn1 stat accumulation ----
// grid 512 = 16 n * 32 htiles ; block 512 (8 waves). Tile: 8 output rows x 256
// cols; stages 10 input rows (+1 halo each side) per channel into LDS.
__global__ __launch_bounds__(512) void k1_conv1(
    const float* __restrict__ x, const float* __restrict__ w1,
    float* __restrict__ h0, float* __restrict__ stats)
{
    __shared__ float tile[10][264];   // interior cols [4..259], zeros at 3/260
    __shared__ float red_s[8], red_q[8];

    const int tid   = threadIdx.x;
    const int bid   = blockIdx.x;
    const int n     = bid >> 5;
    const int ht    = bid & 31;
    const int h0b   = ht << 3;

    const int t     = tid & 255;      // output column
    const int ohb   = (tid >> 8) << 2; // 0 or 4: this thread's 4 output rows
    const int rs    = tid >> 6;       // staging row 0..7
    const int col4  = (tid & 63) << 2;

    float acc0 = 0.f, acc1 = 0.f, acc2 = 0.f, acc3 = 0.f;

    if (tid < 10) { tile[tid][3] = 0.f; tile[tid][260] = 0.f; }

    const float* xn = x + ((size_t)n << 22);   // n * 64 * 65536

    for (int c = 0; c < 64; ++c) {
        __syncthreads();
        // stage rows 0..9  (global rows h0b-1 .. h0b+8), zero-padded
        {
            int g = h0b - 1 + rs;
            float4 v = make_float4(0.f, 0.f, 0.f, 0.f);
            if ((unsigned)g < 256u)
                v = *(const float4*)(xn + ((size_t)c << 16) + (g << 8) + col4);
            *(float4*)&tile[rs][4 + col4] = v;
            if (rs < 2) {
                int g2 = h0b + 7 + rs;
                float4 v2 = make_float4(0.f, 0.f, 0.f, 0.f);
                if ((unsigned)g2 < 256u)
                    v2 = *(const float4*)(xn + ((size_t)c << 16) + (g2 << 8) + col4);
                *(float4*)&tile[8 + rs][4 + col4] = v2;
            }
        }
        __syncthreads();

        float wc[9];
        #pragma unroll
        for (int k = 0; k < 9; ++k) wc[k] = w1[c * 9 + k];

        #pragma unroll
        for (int rr = 0; rr < 6; ++rr) {
            const int sr = ohb + rr;
            float vm = tile[sr][3 + t];
            float v0 = tile[sr][4 + t];
            float vp = tile[sr][5 + t];
            #pragma unroll
            for (int di = 0; di < 3; ++di) {
                const int l = rr - di;   // local output row
                if (l >= 0 && l < 4) {
                    float contrib = wc[di * 3 + 0] * vm + wc[di * 3 + 1] * v0
                                  + wc[di * 3 + 2] * vp;
                    if      (l == 0) acc0 += contrib;
                    else if (l == 1) acc1 += contrib;
                    else if (l == 2) acc2 += contrib;
                    else             acc3 += contrib;
                }
            }
        }
    }

    // write h0 (conv1_b omitted: constant bias cancels in bn1)
    size_t ob = ((size_t)n << 16) + (size_t)((h0b + ohb) << 8) + t;
    h0[ob]       = acc0;
    h0[ob + 256] = acc1;
    h0[ob + 512] = acc2;
    h0[ob + 768] = acc3;

    float s  = acc0 + acc1 + acc2 + acc3;
    float sq = acc0 * acc0 + acc1 * acc1 + acc2 * acc2 + acc3 * acc3;
    #pragma unroll
    for (int o = 32; o > 0; o >>= 1) {
        s  += __shfl_down(s,  o, 64);
        sq += __shfl_down(sq, o, 64);
    }
    const int wave = tid >> 6, lane = tid & 63;
    if (lane == 0) { red_s[wave] = s; red_q[wave] = sq; }
    __syncthreads();
    if (tid == 0) {
        float S = 0.f, Q = 0.f;
        #pragma unroll
        for (int i = 0; i < 8; ++i) { S += red_s[i]; Q += red_q[i]; }
        dev_atomic_add(&stats[0], S);
        dev_atomic_add(&stats[1], Q);
    }
}

// ---------------- K3: bn1 apply + fuzzify (elementwise, float4) -------------
__global__ __launch_bounds__(256) void k3_fuzzify(
    const float* __restrict__ h0, const float* __restrict__ stats,
    const float* __restrict__ bn1_g, const float* __restrict__ bn1_b,
    const float* __restrict__ lb, const float* __restrict__ ub,
    float* __restrict__ fz)
{
    const int i = blockIdx.x * 256 + threadIdx.x;   // float4 index (262144)

    const float mean = stats[0] * INV_NTOT;
    const float var  = stats[1] * INV_NTOT - mean * mean;
    const float rstd = rsqrtf(var + EPS);
    const float A    = bn1_g[0] * rstd;
    const float B    = bn1_b[0] - mean * A;

    float lbv[4], ubv[4];
    #pragma unroll
    for (int f = 0; f < 4; ++f) { lbv[f] = lb[f]; ubv[f] = ub[f]; }

    float4 hv = *(const float4*)(h0 + (size_t)i * 4);
    float in[4] = { hv.x, hv.y, hv.z, hv.w };
    float res[4];
    #pragma unroll
    for (int k = 0; k < 4; ++k) {
        float xv = A * in[k] + B;
        float fuzz = 0.f;
        #pragma unroll
        for (int f = 0; f < 4; ++f) {
            float ld = xv - lbv[f];
            float ud = ubv[f] - xv;
            bool inr  = (ld > 0.f) && (ud > 0.f);
            bool outr = (ld < 0.f) || (ud < 0.f);
            float xr  = 2.f * lbv[f] - xv;
            float u2  = ubv[f] - xr;
            float e1  = __expf(-0.5f * ld * ld);
            float cin  = e1 + __expf(-0.5f * ud * ud);
            float cout = e1 + __expf(-0.5f * u2 * u2);
            fuzz += inr ? cin : (outr ? cout : 0.f);
            xv = outr ? xr : xv;
        }
        res[k] = fuzz;
    }
    *(float4*)(fz + (size_t)i * 4) = make_float4(res[0], res[1], res[2], res[3]);
}

// ---------------- K4: shifted sums S[9] & correlations Q[45] over fz --------
__global__ __launch_bounds__(256) void k4_stats(
    const float* __restrict__ fz, float* __restrict__ stats)
{
    float s9[9], q45[45];
    #pragma unroll
    for (int i = 0; i < 9; ++i)  s9[i]  = 0.f;
    #pragma unroll
    for (int i = 0; i < 45; ++i) q45[i] = 0.f;

    const int base = blockIdx.x * 256 + threadIdx.x;
    for (int k = 0; k < 16; ++k) {
        int p = base + k * 65536;
        int w = p & 255, h = (p >> 8) & 255, n = p >> 16;
        const float* f = fz + ((size_t)n << 16);
        float v[9];
        #pragma unroll
        for (int di = 0; di < 3; ++di)
            #pragma unroll
            for (int dj = 0; dj < 3; ++dj) {
                int hh = h + di - 1, ww = w + dj - 1;
                v[di * 3 + dj] = ((unsigned)hh < 256u && (unsigned)ww < 256u)
                               ? f[(hh << 8) + ww] : 0.f;
            }
        int idx = 0;
        #pragma unroll
        for (int a = 0; a < 9; ++a) {
            s9[a] += v[a];
            #pragma unroll
            for (int b = a; b < 9; ++b) q45[idx++] += v[a] * v[b];
        }
    }

    __shared__ float red[4][54];
    const int wave = threadIdx.x >> 6, lane = threadIdx.x & 63;
    float vals[54];
    #pragma unroll
    for (int i = 0; i < 9; ++i)  vals[i]     = s9[i];
    #pragma unroll
    for (int i = 0; i < 45; ++i) vals[9 + i] = q45[i];
    #pragma unroll
    for (int i = 0; i < 54; ++i) {
        float vv = vals[i];
        #pragma unroll
        for (int o = 32; o > 0; o >>= 1) vv += __shfl_down(vv, o, 64);
        if (lane == 0) red[wave][i] = vv;
    }
    __syncthreads();
    if (threadIdx.x < 54) {
        float tot = red[0][threadIdx.x] + red[1][threadIdx.x]
                  + red[2][threadIdx.x] + red[3][threadIdx.x];
        dev_atomic_add(&stats[2 + threadIdx.x], tot);
    }
}

// ---------------- K5: per-channel bn2 scale/bias from analytic stats --------
__global__ void k5_finalize(
    const float* __restrict__ w2, const float* __restrict__ bn2_g,
    const float* __restrict__ bn2_b, float* __restrict__ stats)
{
    const int c = threadIdx.x;
    if (c >= 64) return;
    float w[9];
    #pragma unroll
    for (int k = 0; k < 9; ++k) w[k] = w2[c * 9 + k];
    float P = 0.f;
    #pragma unroll
    for (int k = 0; k < 9; ++k) P += w[k] * stats[2 + k];
    P *= INV_NTOT;
    float QF = 0.f;
    int idx = 0;
    #pragma unroll
    for (int a = 0; a < 9; ++a)
        #pragma unroll
        for (int b = a; b < 9; ++b) {
            float qv = stats[11 + idx]; idx++;
            QF += w[a] * w[b] * qv * ((a == b) ? 1.f : 2.f);
        }
    QF *= INV_NTOT;
    // conv2_b cancels in bn2 (constant shift removed by mean subtraction)
    float var   = QF - P * P;
    float scale = bn2_g[c] * rsqrtf(var + EPS);
    float bias  = bn2_b[c] - P * scale;
    stats[56 + c]  = scale;
    stats[120 + c] = bias;
}

// ---------------- K6: conv2 (1->64 ch, 3x3 SAME) + bn2 apply ----------------
// grid 1024 = 16 n * 8 * 8 tiles of 32x32 ; block 256, 4 px/thread (float4).
__global__ __launch_bounds__(256) void k6_conv2(
    const float* __restrict__ fz, const float* __restrict__ w2,
    const float* __restrict__ stats, float* __restrict__ out)
{
    __shared__ float tile[34][36];
    const int bid = blockIdx.x;
    const int n   = bid >> 6;
    const int th  = (bid >> 3) & 7;
    const int tw  = bid & 7;
    const int h0b = th << 5, w0b = tw << 5;
    const int tid = threadIdx.x;

    const float* f = fz + ((size_t)n << 16);
    for (int i = tid; i < 34 * 34; i += 256) {
        int rr = i / 34, cc = i - rr * 34;
        int gh = h0b + rr - 1, gw = w0b + cc - 1;
        tile[rr][cc] = ((unsigned)gh < 256u && (unsigned)gw < 256u)
                     ? f[(gh << 8) + gw] : 0.f;
    }
    __syncthreads();

    const int r = tid >> 3, q = tid & 7;
    float v[3][6];
    #pragma unroll
    for (int di = 0; di < 3; ++di)
        #pragma unroll
        for (int j = 0; j < 6; ++j)
            v[di][j] = tile[r + di][(q << 2) + j];

    const size_t ob = ((size_t)n << 22) + (size_t)((h0b + r) << 8) + w0b + (q << 2);
    for (int c = 0; c < 64; ++c) {
        float wk[9];
        #pragma unroll
        for (int k = 0; k < 9; ++k) wk[k] = w2[c * 9 + k];
        const float sc = stats[56 + c], bi = stats[120 + c];
        float4 o;
        float* op = &o.x;
        #pragma unroll
        for (int k = 0; k < 4; ++k) {
            float y = 0.f;
            #pragma unroll
            for (int di = 0; di < 3; ++di)
                y += wk[di * 3 + 0] * v[di][k]
                   + wk[di * 3 + 1] * v[di][k + 1]
                   + wk[di * 3 + 2] * v[di][k + 2];
            op[k] = y * sc + bi;
        }
        *(float4*)(out + ob + ((size_t)c << 16)) = o;
    }
}

extern "C" void kernel_launch(void* const* d_in, const int* in_sizes, int n_in,
                              void* d_out, int out_size, void* d_ws, size_t ws_size,
                              hipStream_t stream)
{
    const float* x  = (const float*)d_in[0];
    const float* w1 = (const float*)d_in[1];
    // d_in[2] = conv1_b : cancels under bn1 (training mode) -> unused
    const float* w2 = (const float*)d_in[3];
    // d_in[4] = conv2_b : cancels under bn2 -> unused
    const float* g1 = (const float*)d_in[5];
    const float* b1 = (const float*)d_in[6];
    const float* g2 = (const float*)d_in[7];
    const float* b2 = (const float*)d_in[8];
    const float* lb = (const float*)d_in[9];
    const float* ub = (const float*)d_in[10];

    float* ws  = (float*)d_ws;
    float* h0  = ws;
    float* fz  = ws + FZ_OFF;
    float* st  = ws + ST_OFF;
    float* out = (float*)d_out;

    hipMemsetAsync(st, 0, 56 * sizeof(float), stream);            // sum,sumsq,S,Q
    k1_conv1  <<<dim3(512),  dim3(512), 0, stream>>>(x, w1, h0, st);
    k3_fuzzify<<<dim3(1024), dim3(256), 0, stream>>>(h0, st, g1, b1, lb, ub, fz);
    k4_stats  <<<dim3(256),  dim3(256), 0, stream>>>(fz, st);
    k5_finalize<<<dim3(1),   dim3(64),  0, stream>>>(w2, g2, b2, st);
    k6_conv2  <<<dim3(1024), dim3(256), 0, stream>>>(fz, w2, st, out);
}